// Round 1
// baseline (208.969 us; speedup 1.0000x reference)
//
#include <hip/hip_runtime.h>
#include <math.h>

#define NCTX 1024
#define DIN 512
#define NH 8
#define DH 64

// workspace layout in floats
#define WS_Q 0
#define WS_K (4 * NH * NCTX * DH)          // 2,097,152
#define WS_V (2 * 4 * NH * NCTX * DH)      // 4,194,304

__device__ __forceinline__ void softmax8(const float* __restrict__ w,
                                         float* __restrict__ p) {
  float mx = w[0];
#pragma unroll
  for (int v = 1; v < 8; ++v) mx = fmaxf(mx, w[v]);
  float s = 0.f;
#pragma unroll
  for (int v = 0; v < 8; ++v) { p[v] = expf(w[v] - mx); s += p[v]; }
  const float inv = 1.f / s;
#pragma unroll
  for (int v = 0; v < 8; ++v) p[v] *= inv;
}

// Kernel 1: build Q (transposed [h][p]), K (transposed [h][p]), V ([p][h]) in ws.
__global__ __launch_bounds__(256) void prep_kernel(
    const float* __restrict__ x, const float* __restrict__ WKw,
    const float* __restrict__ WQw, const float* __restrict__ WVw,
    const float* __restrict__ Wpred, float* __restrict__ ws) {
  const int pt = blockIdx.x, i = blockIdx.y, b = blockIdx.z;
  const int p0 = pt * 64;
  const int bi = b * NH + i;
  const int tid = threadIdx.x;

  __shared__ float Q0s[64][65];
  __shared__ float Ts[64][65];
  __shared__ float Wps[64][64];

  // Wp[i] = softmax(W_pred_W[i], axis=-1): 64 rows, one per thread < 64
  if (tid < 64) {
    const float* wrow = Wpred + (size_t)(i * 64 + tid) * 64;
    float mx = -1e30f;
    for (int f = 0; f < 64; ++f) mx = fmaxf(mx, wrow[f]);
    float s = 0.f;
    for (int f = 0; f < 64; ++f) s += expf(wrow[f] - mx);
    const float inv = 1.f / s;
    for (int f = 0; f < 64; ++f) Wps[tid][f] = expf(wrow[f] - mx) * inv;
  }

  float pk[8], pq[8], pv[8];
  {
    float w[8];
#pragma unroll
    for (int v = 0; v < 8; ++v) w[v] = WKw[i * 8 + v];
    softmax8(w, pk);
#pragma unroll
    for (int v = 0; v < 8; ++v) w[v] = WQw[i * 8 + v];
    softmax8(w, pq);
#pragma unroll
    for (int v = 0; v < 8; ++v) w[v] = WVw[i * 8 + v];
    softmax8(w, pv);
  }

  float* Qw = ws + WS_Q;
  float* Kw = ws + WS_K;
  float* Vw = ws + WS_V;

  // Stage A: load x, compute mixes. V written directly (row-major), K kept in
  // regs for LDS transpose, Q0 to LDS for the @Wp matmul.
  float kreg[16];
#pragma unroll
  for (int k = 0; k < 16; ++k) {
    const int idx = k * 256 + tid;
    const int r = idx >> 6, e = idx & 63;
    const float* xp = x + ((size_t)(b * NCTX + p0 + r)) * DIN + e;
    float q0 = 0.f, kk = 0.f, vv = 0.f;
#pragma unroll
    for (int v = 0; v < 8; ++v) {
      const float xv = xp[v * 64];
      q0 = fmaf(pq[v], xv, q0);
      kk = fmaf(pk[v], xv, kk);
      vv = fmaf(pv[v], xv, vv);
    }
    Q0s[r][e] = q0;
    kreg[k] = kk;
    Vw[((size_t)bi * NCTX + p0 + r) * DH + e] = vv;
  }
  __syncthreads();

  // Stage B: K into Ts transposed
#pragma unroll
  for (int k = 0; k < 16; ++k) {
    const int r = k * 4 + (tid >> 6), e = tid & 63;
    Ts[e][r] = kreg[k];
  }
  __syncthreads();

  // Stage C: coalesced K write (layout [h][p])
#pragma unroll
  for (int k = 0; k < 16; ++k) {
    const int idx = k * 256 + tid;
    const int h = idx >> 6, r = idx & 63;
    Kw[((size_t)bi * DH + h) * NCTX + p0 + r] = Ts[h][r];
  }

  // Stage D: Q = Q0 @ Wp (into regs)
  float qreg[16];
#pragma unroll
  for (int k = 0; k < 16; ++k) {
    const int idx = k * 256 + tid;
    const int r = idx >> 6, h = idx & 63;
    float acc = 0.f;
#pragma unroll
    for (int e = 0; e < 64; ++e) acc = fmaf(Q0s[r][e], Wps[e][h], acc);
    qreg[k] = acc;
  }
  __syncthreads();

  // Stage E: Q into Ts transposed
#pragma unroll
  for (int k = 0; k < 16; ++k) {
    const int r = k * 4 + (tid >> 6), h = tid & 63;
    Ts[h][r] = qreg[k];
  }
  __syncthreads();

  // Stage F: coalesced Q write (layout [h][p])
#pragma unroll
  for (int k = 0; k < 16; ++k) {
    const int idx = k * 256 + tid;
    const int h = idx >> 6, r = idx & 63;
    Qw[((size_t)bi * DH + h) * NCTX + p0 + r] = Ts[h][r];
  }
}

// Kernel 2: causal attention with log-bias softmax and p=0 correction.
// Block handles q-tiles {P, 15-P} -> exactly 17 p-tiles per block (balanced).
__global__ __launch_bounds__(256) void attn_kernel(
    const float* __restrict__ ws, float* __restrict__ out) {
  const int P = blockIdx.x;  // 0..7
  const int i = blockIdx.y, b = blockIdx.z;
  const int bi = b * NH + i;
  const int tid = threadIdx.x;
  const int lane = tid & 63;
  const int wid = tid >> 6;
  const int trl = lane >> 4;   // 0..3
  const int tc = lane & 15;    // 0..15
  const int R = wid * 4 + trl; // row group 0..15
  const int r0 = 4 * R;
  const int h0 = 4 * tc;

  const float* Qg = ws + WS_Q + (size_t)bi * DH * NCTX;  // [h][p]
  const float* Kg = ws + WS_K + (size_t)bi * DH * NCTX;  // [h][p]
  const float* Vg = ws + WS_V + (size_t)bi * NCTX * DH;  // [p][h]

  __shared__ float QsT[64][68];
  __shared__ float KsT[64][68];
  __shared__ float Vs[64][68];
  __shared__ float Wls[64][68];

#pragma unroll 1
  for (int which = 0; which < 2; ++which) {
    const int qt = which ? (15 - P) : P;
    const int q0 = qt * 64;

    __syncthreads();  // protect QsT/Vs/Wls from previous iteration readers
#pragma unroll
    for (int k = 0; k < 4; ++k) {
      const int idx = k * 256 + tid;
      const int h = idx >> 4, c4 = idx & 15;
      *(float4*)&QsT[h][4 * c4] =
          *(const float4*)(Qg + (size_t)h * NCTX + q0 + 4 * c4);
    }

    float num[4][4];
#pragma unroll
    for (int a = 0; a < 4; ++a)
#pragma unroll
      for (int j = 0; j < 4; ++j) num[a][j] = 0.f;
    float den[4] = {0.f, 0.f, 0.f, 0.f};
    float srw[4] = {0.f, 0.f, 0.f, 0.f};
    float pre0c[4] = {0.f, 0.f, 0.f, 0.f};

    for (int pt = 0; pt <= qt; ++pt) {
      const int p0 = pt * 64;
      __syncthreads();
#pragma unroll
      for (int k = 0; k < 4; ++k) {
        const int idx = k * 256 + tid;
        const int rr = idx >> 4, c4 = idx & 15;
        *(float4*)&KsT[rr][4 * c4] =
            *(const float4*)(Kg + (size_t)rr * NCTX + p0 + 4 * c4);
        *(float4*)&Vs[rr][4 * c4] =
            *(const float4*)(Vg + (size_t)(p0 + rr) * DH + 4 * c4);
      }
      __syncthreads();

      // S = Q K^T, 4x4 register tile per thread
      float s[4][4];
#pragma unroll
      for (int a = 0; a < 4; ++a)
#pragma unroll
        for (int j = 0; j < 4; ++j) s[a][j] = 0.f;

#pragma unroll 8
      for (int h = 0; h < 64; ++h) {
        const float4 qa = *(const float4*)&QsT[h][r0];
        const float4 kb = *(const float4*)&KsT[h][4 * tc];
        s[0][0] = fmaf(qa.x, kb.x, s[0][0]);
        s[0][1] = fmaf(qa.x, kb.y, s[0][1]);
        s[0][2] = fmaf(qa.x, kb.z, s[0][2]);
        s[0][3] = fmaf(qa.x, kb.w, s[0][3]);
        s[1][0] = fmaf(qa.y, kb.x, s[1][0]);
        s[1][1] = fmaf(qa.y, kb.y, s[1][1]);
        s[1][2] = fmaf(qa.y, kb.z, s[1][2]);
        s[1][3] = fmaf(qa.y, kb.w, s[1][3]);
        s[2][0] = fmaf(qa.z, kb.x, s[2][0]);
        s[2][1] = fmaf(qa.z, kb.y, s[2][1]);
        s[2][2] = fmaf(qa.z, kb.z, s[2][2]);
        s[2][3] = fmaf(qa.z, kb.w, s[2][3]);
        s[3][0] = fmaf(qa.w, kb.x, s[3][0]);
        s[3][1] = fmaf(qa.w, kb.y, s[3][1]);
        s[3][2] = fmaf(qa.w, kb.z, s[3][2]);
        s[3][3] = fmaf(qa.w, kb.w, s[3][3]);
      }

      // transform: w = (pre+1e-20)^(1/8) * exp(bias/8); track srow, pre0
#pragma unroll
      for (int a = 0; a < 4; ++a) {
        const int qg = q0 + r0 + a;
        float w4[4];
#pragma unroll
        for (int j = 0; j < 4; ++j) {
          const int pg = p0 + 4 * tc + j;
          const float pre = s[a][j];
          const int d = qg - pg;
          float w = 0.f;
          if (d >= 0) {
            const float bias =
                (d == 0) ? -2.0f : (1.0f - (float)d) * (1.0f / 1023.0f);
            srw[a] += pre;
            w = __expf(0.125f * (__logf(pre + 1e-20f) + bias));
          }
          den[a] += w;
          if (pg == 0) pre0c[a] = pre;
          w4[j] = w;
        }
        *(float4*)&Wls[r0 + a][4 * tc] =
            make_float4(w4[0], w4[1], w4[2], w4[3]);
      }
      __syncthreads();

      // num += W * V  (thread owns rows r0..r0+3, h-cols h0..h0+3)
#pragma unroll 4
      for (int cc = 0; cc < 16; ++cc) {
        const float4 vA = *(const float4*)&Vs[4 * cc + 0][h0];
        const float4 vB = *(const float4*)&Vs[4 * cc + 1][h0];
        const float4 vC = *(const float4*)&Vs[4 * cc + 2][h0];
        const float4 vD = *(const float4*)&Vs[4 * cc + 3][h0];
#pragma unroll
        for (int a = 0; a < 4; ++a) {
          const float4 w4 = *(const float4*)&Wls[r0 + a][4 * cc];
          num[a][0] += w4.x * vA.x + w4.y * vB.x + w4.z * vC.x + w4.w * vD.x;
          num[a][1] += w4.x * vA.y + w4.y * vB.y + w4.z * vC.y + w4.w * vD.y;
          num[a][2] += w4.x * vA.z + w4.y * vB.z + w4.z * vC.z + w4.w * vD.z;
          num[a][3] += w4.x * vA.w + w4.y * vB.w + w4.z * vC.w + w4.w * vD.w;
        }
      }
    }  // pt

    // finalize: reduce srow/den over the 16 lanes of the row group, apply
    // the p=0 relu correction, normalize, write out.
    const float4 v0 = *(const float4*)(Vg + h0);  // V[p=0][h0..h0+3]
#pragma unroll
    for (int a = 0; a < 4; ++a) {
      float sr = srw[a], dn = den[a];
#pragma unroll
      for (int off = 1; off < 16; off <<= 1) {
        sr += __shfl_xor(sr, off, 16);
        dn += __shfl_xor(dn, off, 16);
      }
      const float pre0 = __shfl(pre0c[a], 0, 16);
      const int qg = q0 + r0 + a;
      const float ms = sr / (sr + 1e-10f);
      const float add = fmaxf(1.f - ms, 0.f);
      const float bias =
          (qg == 0) ? -2.0f : (1.0f - (float)qg) * (1.0f / 1023.0f);
      const float w0n = __expf(0.125f * (__logf(pre0 + add + 1e-20f) + bias));
      const float w0o = __expf(0.125f * (__logf(pre0 + 1e-20f) + bias));
      const float dw = w0n - w0o;
      dn += dw;
      const float inv = 1.f / dn;
      float4 o;
      o.x = (num[a][0] + dw * v0.x) * inv;
      o.y = (num[a][1] + dw * v0.y) * inv;
      o.z = (num[a][2] + dw * v0.z) * inv;
      o.w = (num[a][3] + dw * v0.w) * inv;
      *(float4*)(out + ((size_t)b * NCTX + qg) * DIN + i * DH + h0) = o;
    }
  }  // which
}

extern "C" void kernel_launch(void* const* d_in, const int* in_sizes, int n_in,
                              void* d_out, int out_size, void* d_ws,
                              size_t ws_size, hipStream_t stream) {
  const float* x = (const float*)d_in[0];
  // d_in[1] is the mask: known causal tril, not needed.
  const float* WKw = (const float*)d_in[2];
  const float* WQw = (const float*)d_in[3];
  const float* WVw = (const float*)d_in[4];
  const float* Wpred = (const float*)d_in[5];
  float* ws = (float*)d_ws;
  float* out = (float*)d_out;

  dim3 block(256);
  dim3 grid1(16, NH, 4);
  hipLaunchKernelGGL(prep_kernel, grid1, block, 0, stream, x, WKw, WQw, WVw,
                     Wpred, ws);
  dim3 grid2(8, NH, 4);
  hipLaunchKernelGGL(attn_kernel, grid2, block, 0, stream, ws, out);
}

// Round 2
// 46.362 us; speedup vs baseline: 4.5074x; 4.5074x over previous
//
#include <hip/hip_runtime.h>
#include <math.h>

#define NCTX 1024
#define DIN 512
#define NH 8
#define DH 64

typedef float f32x16 __attribute__((ext_vector_type(16)));
typedef short bf16x8 __attribute__((ext_vector_type(8)));
typedef int i32x4 __attribute__((ext_vector_type(4)));

// ws byte offsets: Qf 4MB | Kf 4MB | Vf 4MB | V0f 8KB
#define QF_OFF 0
#define KF_OFF (4u * 1024u * 1024u)
#define VF_OFF (8u * 1024u * 1024u)
#define V0_OFF (12u * 1024u * 1024u)

__device__ __forceinline__ unsigned short f2bf(float f) {
  unsigned u = __float_as_uint(f);
  unsigned r = u + 0x7FFFu + ((u >> 16) & 1u);
  return (unsigned short)(r >> 16);
}

__device__ __forceinline__ bf16x8 asbf(i32x4 v) {
  union { i32x4 i; bf16x8 h; } u;
  u.i = v;
  return u.h;
}

__device__ __forceinline__ bf16x8 mk8(unsigned a, unsigned b, unsigned c,
                                      unsigned d) {
  union { unsigned u[4]; bf16x8 h; } x;
  x.u[0] = a; x.u[1] = b; x.u[2] = c; x.u[3] = d;
  return x.h;
}

__device__ __forceinline__ unsigned cvtpk(float lo, float hi_) {
  unsigned r;
  asm("v_cvt_pk_bf16_f32 %0, %1, %2" : "=v"(r) : "v"(lo), "v"(hi_));
  return r;
}

__device__ __forceinline__ void softmax8(const float* __restrict__ w,
                                         float* __restrict__ p) {
  float mx = w[0];
#pragma unroll
  for (int v = 1; v < 8; ++v) mx = fmaxf(mx, w[v]);
  float s = 0.f;
#pragma unroll
  for (int v = 0; v < 8; ++v) { p[v] = expf(w[v] - mx); s += p[v]; }
  const float inv = 1.f / s;
#pragma unroll
  for (int v = 0; v < 8; ++v) p[v] *= inv;
}

// Kernel 1: build MFMA fragments.
// Qf[bi][qt][qq][kk][lane][i] = Q[32qq+l%32][16kk+8*(l>>5)+i]      (B-op of St)
// Kf[bi][pt][pq][kk][lane][i] = K[32pq+l%32][16kk+8*(l>>5)+i]      (A-op of St)
// Vf[bi][pt][pq][kk2][hh][lane][i] = V[32pq+16kk2+8*(l>>5)+i][32hh+l%32] (B-op PV)
__global__ __launch_bounds__(256) void prep_kernel(
    const float* __restrict__ x, const float* __restrict__ WKw,
    const float* __restrict__ WQw, const float* __restrict__ WVw,
    const float* __restrict__ Wpred, short* __restrict__ Qf,
    short* __restrict__ Kf, short* __restrict__ Vf, float* __restrict__ V0f) {
  const int t = blockIdx.x, i = blockIdx.y, b = blockIdx.z;
  const int bi = b * NH + i;
  const int tid = threadIdx.x;

  __shared__ float Q0s[64][68];
  __shared__ float Ks[64][68];
  __shared__ float Vs[64][68];
  __shared__ float Wps[64][64];

  // Wp softmax: 4 threads per row, 16 elems each
  {
    const int row = tid >> 2, sg = tid & 3;
    const float* wr = Wpred + (size_t)(i * 64 + row) * 64 + sg * 16;
    float e16[16];
    float mx = -1e30f;
#pragma unroll
    for (int j = 0; j < 16; ++j) { e16[j] = wr[j]; mx = fmaxf(mx, e16[j]); }
    mx = fmaxf(mx, __shfl_xor(mx, 1, 4));
    mx = fmaxf(mx, __shfl_xor(mx, 2, 4));
    float s = 0.f;
#pragma unroll
    for (int j = 0; j < 16; ++j) { e16[j] = __expf(e16[j] - mx); s += e16[j]; }
    s += __shfl_xor(s, 1, 4);
    s += __shfl_xor(s, 2, 4);
    const float inv = 1.f / s;
#pragma unroll
    for (int j = 0; j < 16; ++j) Wps[row][sg * 16 + j] = e16[j] * inv;
  }

  float pk[8], pq8[8], pv[8];
  {
    float w[8];
#pragma unroll
    for (int v = 0; v < 8; ++v) w[v] = WKw[i * 8 + v];
    softmax8(w, pk);
#pragma unroll
    for (int v = 0; v < 8; ++v) w[v] = WQw[i * 8 + v];
    softmax8(w, pq8);
#pragma unroll
    for (int v = 0; v < 8; ++v) w[v] = WVw[i * 8 + v];
    softmax8(w, pv);
  }

  // Stage A: coalesced x loads, compute mixes into LDS
#pragma unroll
  for (int k = 0; k < 16; ++k) {
    const int idx = k * 256 + tid;
    const int r = idx >> 6, e = idx & 63;
    const float* xp = x + ((size_t)(b * NCTX + t * 64 + r)) * DIN + e;
    float q0 = 0.f, kk = 0.f, vv = 0.f;
#pragma unroll
    for (int v = 0; v < 8; ++v) {
      const float xv = xp[v * 64];
      q0 = fmaf(pq8[v], xv, q0);
      kk = fmaf(pk[v], xv, kk);
      vv = fmaf(pv[v], xv, vv);
    }
    Q0s[r][e] = q0;
    Ks[r][e] = kk;
    Vs[r][e] = vv;
    if (t == 0 && k == 0 && tid < 64) V0f[bi * 64 + e] = vv;
  }
  __syncthreads();

  const int wv = tid >> 6;
  const int l = tid & 63;
  const int hi = l >> 5;
  const int lm = l & 31;

  // K fragments
  {
    const int pq = wv & 1;
    const int p = 32 * pq + lm;
#pragma unroll
    for (int c = 0; c < 2; ++c) {
      const int kk = (wv >> 1) * 2 + c;
      const int hb = 16 * kk + 8 * hi;
      const float4 a = *(const float4*)&Ks[p][hb];
      const float4 bq = *(const float4*)&Ks[p][hb + 4];
      bf16x8 vv;
      vv[0] = (short)f2bf(a.x); vv[1] = (short)f2bf(a.y);
      vv[2] = (short)f2bf(a.z); vv[3] = (short)f2bf(a.w);
      vv[4] = (short)f2bf(bq.x); vv[5] = (short)f2bf(bq.y);
      vv[6] = (short)f2bf(bq.z); vv[7] = (short)f2bf(bq.w);
      const size_t off = (size_t)bi * 8192 + (size_t)t * 512 + pq * 256 +
                         kk * 64 + l;
      ((bf16x8*)Kf)[off] = vv;
    }
  }

  // V fragments
  {
    const int pq = wv & 1;
    const int kk2 = wv >> 1;
#pragma unroll
    for (int hh = 0; hh < 2; ++hh) {
      const int pr = 32 * pq + 16 * kk2 + 8 * hi;
      const int hc = 32 * hh + lm;
      bf16x8 vv;
#pragma unroll
      for (int ii = 0; ii < 8; ++ii) vv[ii] = (short)f2bf(Vs[pr + ii][hc]);
      const size_t off = (size_t)bi * 8192 + (size_t)t * 512 + pq * 256 +
                         (kk2 * 2 + hh) * 64 + l;
      ((bf16x8*)Vf)[off] = vv;
    }
  }

  // Q = Q0 @ Wp, emitted directly in fragment order
  {
    const int qq = wv & 1;
    const int qrow = 32 * qq + lm;
#pragma unroll
    for (int c = 0; c < 2; ++c) {
      const int kk = (wv >> 1) * 2 + c;
      const int hb = 16 * kk + 8 * hi;
      float acc[8];
#pragma unroll
      for (int j = 0; j < 8; ++j) acc[j] = 0.f;
      for (int e = 0; e < 64; ++e) {
        const float q0v = Q0s[qrow][e];
        const float4 wa = *(const float4*)&Wps[e][hb];
        const float4 wb = *(const float4*)&Wps[e][hb + 4];
        acc[0] = fmaf(q0v, wa.x, acc[0]);
        acc[1] = fmaf(q0v, wa.y, acc[1]);
        acc[2] = fmaf(q0v, wa.z, acc[2]);
        acc[3] = fmaf(q0v, wa.w, acc[3]);
        acc[4] = fmaf(q0v, wb.x, acc[4]);
        acc[5] = fmaf(q0v, wb.y, acc[5]);
        acc[6] = fmaf(q0v, wb.z, acc[6]);
        acc[7] = fmaf(q0v, wb.w, acc[7]);
      }
      bf16x8 vv;
#pragma unroll
      for (int j = 0; j < 8; ++j) vv[j] = (short)f2bf(acc[j]);
      const size_t off = (size_t)bi * 8192 + (size_t)t * 512 + qq * 256 +
                         kk * 64 + l;
      ((bf16x8*)Qf)[off] = vv;
    }
  }
}

// Kernel 2: MFMA attention. One block per (bi, qt), 4 waves: pq=wv&1, qq=wv>>1.
__global__ __launch_bounds__(256) void attn_kernel(
    const short* __restrict__ Qf, const short* __restrict__ Kf,
    const short* __restrict__ Vf, const float* __restrict__ V0f,
    float* __restrict__ out) {
  const int bx = blockIdx.x;
  const int a = bx >> 5;
  const int bi = bx & 31;
  const int qt = (a < 8) ? (15 - a) : (a - 8);  // heavy-first, pair-sum 15
  const int b = bi >> 3, ih = bi & 7;
  const int tid = threadIdx.x;
  const int wv = tid >> 6;
  const int l = tid & 63;
  const int hi = l >> 5;
  const int lm = l & 31;
  const int pq = wv & 1;
  const int qq = wv >> 1;

  __shared__ float num_l[2][32][64];
  __shared__ float rdn[2][2][32];
  __shared__ float rsw[2][2][32];
  __shared__ float rp0[2][32];
  __shared__ float rdw[2][32];
  __shared__ float rinv[2][32];

  const i32x4* Qp = (const i32x4*)Qf + (size_t)bi * 8192 + (size_t)qt * 512 +
                    qq * 256;
  const i32x4* Kp = (const i32x4*)Kf + (size_t)bi * 8192 + pq * 256;
  const i32x4* Vp = (const i32x4*)Vf + (size_t)bi * 8192 + pq * 256;

  bf16x8 qfr[4];
#pragma unroll
  for (int kk = 0; kk < 4; ++kk) qfr[kk] = asbf(Qp[kk * 64 + l]);

  const float v0a = V0f[bi * 64 + lm];
  const float v0b = V0f[bi * 64 + 32 + lm];

  f32x16 num0, num1;
#pragma unroll
  for (int r = 0; r < 16; ++r) { num0[r] = 0.f; num1[r] = 0.f; }
  float den = 0.f, srw = 0.f, pre0 = 0.f;
  const int qg = qt * 64 + 32 * qq + lm;
  const float BC = 0.125f / 1023.0f;

  i32x4 kA[4], vA[4], kB[4], vB[4];

#define LOADKV(PT, S)                                                   \
  do {                                                                  \
    const size_t o_ = (size_t)(PT) * 512;                               \
    _Pragma("unroll") for (int kk = 0; kk < 4; ++kk)                    \
        k##S[kk] = Kp[o_ + kk * 64 + l];                                \
    _Pragma("unroll") for (int j = 0; j < 4; ++j)                       \
        v##S[j] = Vp[o_ + j * 64 + l];                                  \
  } while (0)

#define STEP(PT, S)                                                          \
  do {                                                                       \
    f32x16 st;                                                               \
    _Pragma("unroll") for (int r = 0; r < 16; ++r) st[r] = 0.f;              \
    _Pragma("unroll") for (int kk = 0; kk < 4; ++kk) st =                    \
        __builtin_amdgcn_mfma_f32_32x32x16_bf16(asbf(k##S[kk]), qfr[kk], st, \
                                                0, 0, 0);                    \
    const int pb_ = (PT) * 64 + 32 * pq + 4 * hi;                            \
    float w_[16];                                                            \
    _Pragma("unroll") for (int r = 0; r < 16; ++r) {                         \
      const int pg = pb_ + ((r & 3) + 8 * (r >> 2));                         \
      const int d = qg - pg;                                                 \
      const float pre = st[r];                                               \
      const float b8 = (d == 0) ? -0.25f : fmaf((float)d, -BC, BC);          \
      const bool ok = d >= 0;                                                \
      const float ww =                                                       \
          ok ? __expf(fmaf(0.125f, __logf(pre + 1e-20f), b8)) : 0.f;         \
      den += ww;                                                             \
      srw += ok ? pre : 0.f;                                                 \
      w_[r] = ww;                                                            \
    }                                                                        \
    if ((PT) == 0 && pq == 0 && hi == 0) pre0 = st[0];                       \
    _Pragma("unroll") for (int c = 0; c < 2; ++c) {                          \
      const float u0 = w_[8 * c + 0], u1 = w_[8 * c + 1];                    \
      const float u2 = w_[8 * c + 2], u3 = w_[8 * c + 3];                    \
      const float u4 = w_[8 * c + 4], u5 = w_[8 * c + 5];                    \
      const float u6 = w_[8 * c + 6], u7 = w_[8 * c + 7];                    \
      const float t0 = __shfl_xor(u0, 32, 64);                               \
      const float t1 = __shfl_xor(u1, 32, 64);                               \
      const float t2 = __shfl_xor(u2, 32, 64);                               \
      const float t3 = __shfl_xor(u3, 32, 64);                               \
      const float t4 = __shfl_xor(u4, 32, 64);                               \
      const float t5 = __shfl_xor(u5, 32, 64);                               \
      const float t6 = __shfl_xor(u6, 32, 64);                               \
      const float t7 = __shfl_xor(u7, 32, 64);                               \
      const bool h1 = hi != 0;                                               \
      const unsigned F0 = cvtpk(h1 ? t4 : u0, h1 ? t5 : u1);                 \
      const unsigned F1 = cvtpk(h1 ? t6 : u2, h1 ? t7 : u3);                 \
      const unsigned F2 = cvtpk(h1 ? u4 : t0, h1 ? u5 : t1);                 \
      const unsigned F3 = cvtpk(h1 ? u6 : t2, h1 ? u7 : t3);                 \
      const bf16x8 wf = mk8(F0, F1, F2, F3);                                 \
      num0 = __builtin_amdgcn_mfma_f32_32x32x16_bf16(wf, asbf(v##S[2 * c]),  \
                                                     num0, 0, 0, 0);         \
      num1 = __builtin_amdgcn_mfma_f32_32x32x16_bf16(                        \
          wf, asbf(v##S[2 * c + 1]), num1, 0, 0, 0);                         \
    }                                                                        \
  } while (0)

  LOADKV(0, A);
  for (int pt = 0; pt <= qt; pt += 2) {
    if (pt + 1 <= qt) LOADKV(pt + 1, B);
    STEP(pt, A);
    if (pt + 1 > qt) break;
    if (pt + 2 <= qt) LOADKV(pt + 2, A);
    STEP(pt + 1, B);
  }

  // cross-wave (pq) reduction
  const float dsum = den + __shfl_xor(den, 32, 64);
  const float ssum = srw + __shfl_xor(srw, 32, 64);
  if (hi == 0) {
    rdn[qq][pq][lm] = dsum;
    rsw[qq][pq][lm] = ssum;
    if (pq == 0) rp0[qq][lm] = pre0;
  }
  if (pq == 1) {
#pragma unroll
    for (int r = 0; r < 16; ++r) {
      const int row = (r & 3) + 8 * (r >> 2) + 4 * hi;
      num_l[qq][row][lm] = num0[r];
      num_l[qq][row][32 + lm] = num1[r];
    }
  }
  __syncthreads();
  if (pq == 1 && hi == 0) {
    const int q = lm;
    const float dtot = rdn[qq][0][q] + rdn[qq][1][q];
    const float stot = rsw[qq][0][q] + rsw[qq][1][q];
    const float p0v = rp0[qq][q];
    const float ms = stot / (stot + 1e-10f);
    const float add = fmaxf(1.f - ms, 0.f);
    const int qgq = qt * 64 + qq * 32 + q;
    const float b8 =
        (qgq == 0) ? -0.25f : (1.0f - (float)qgq) * (0.125f / 1023.0f);
    const float w0n = __expf(fmaf(0.125f, __logf(p0v + add + 1e-20f), b8));
    const float w0o = __expf(fmaf(0.125f, __logf(p0v + 1e-20f), b8));
    const float dwv = w0n - w0o;
    rdw[qq][q] = dwv;
    rinv[qq][q] = 1.f / (dtot + dwv);
  }
  __syncthreads();
  if (pq == 0) {
#pragma unroll
    for (int r = 0; r < 16; ++r) {
      const int row = (r & 3) + 8 * (r >> 2) + 4 * hi;
      const int qgq = qt * 64 + qq * 32 + row;
      const float dwv = rdw[qq][row];
      const float iv = rinv[qq][row];
      const float o0 = (num0[r] + num_l[qq][row][lm] + dwv * v0a) * iv;
      const float o1 = (num1[r] + num_l[qq][row][32 + lm] + dwv * v0b) * iv;
      float* op = out + ((size_t)b * NCTX + qgq) * DIN + ih * DH;
      op[lm] = o0;
      op[32 + lm] = o1;
    }
  }
#undef LOADKV
#undef STEP
}

extern "C" void kernel_launch(void* const* d_in, const int* in_sizes, int n_in,
                              void* d_out, int out_size, void* d_ws,
                              size_t ws_size, hipStream_t stream) {
  const float* x = (const float*)d_in[0];
  const float* WKw = (const float*)d_in[2];
  const float* WQw = (const float*)d_in[3];
  const float* WVw = (const float*)d_in[4];
  const float* Wpred = (const float*)d_in[5];
  float* out = (float*)d_out;

  short* Qf = (short*)((char*)d_ws + QF_OFF);
  short* Kf = (short*)((char*)d_ws + KF_OFF);
  short* Vf = (short*)((char*)d_ws + VF_OFF);
  float* V0f = (float*)((char*)d_ws + V0_OFF);

  dim3 block(256);
  dim3 grid1(16, NH, 4);
  hipLaunchKernelGGL(prep_kernel, grid1, block, 0, stream, x, WKw, WQw, WVw,
                     Wpred, Qf, Kf, Vf, V0f);
  dim3 grid2(512);
  hipLaunchKernelGGL(attn_kernel, grid2, block, 0, stream, Qf, Kf, Vf, V0f,
                     out);
}

// Round 3
// 40.417 us; speedup vs baseline: 5.1704x; 1.1471x over previous
//
#include <hip/hip_runtime.h>
#include <math.h>

#define NCTX 1024
#define DIN 512
#define NH 8
#define DH 64

typedef float f32x16 __attribute__((ext_vector_type(16)));
typedef short bf16x8 __attribute__((ext_vector_type(8)));
typedef int i32x4 __attribute__((ext_vector_type(4)));

// ws byte offsets: Qf 4MB | Kf 4MB | Vf 4MB | V0f 8KB
#define QF_OFF 0
#define KF_OFF (4u * 1024u * 1024u)
#define VF_OFF (8u * 1024u * 1024u)
#define V0_OFF (12u * 1024u * 1024u)

__device__ __forceinline__ bf16x8 asbf(i32x4 v) {
  union { i32x4 i; bf16x8 h; } u;
  u.i = v;
  return u.h;
}

__device__ __forceinline__ bf16x8 mk8(unsigned a, unsigned b, unsigned c,
                                      unsigned d) {
  union { unsigned u[4]; bf16x8 h; } x;
  x.u[0] = a; x.u[1] = b; x.u[2] = c; x.u[3] = d;
  return x.h;
}

__device__ __forceinline__ unsigned cvtpk(float lo, float hi_) {
  unsigned r;
  asm("v_cvt_pk_bf16_f32 %0, %1, %2" : "=v"(r) : "v"(lo), "v"(hi_));
  return r;
}

__device__ __forceinline__ void softmax8(const float* __restrict__ w,
                                         float* __restrict__ p) {
  float mx = w[0];
#pragma unroll
  for (int v = 1; v < 8; ++v) mx = fmaxf(mx, w[v]);
  float s = 0.f;
#pragma unroll
  for (int v = 0; v < 8; ++v) { p[v] = expf(w[v] - mx); s += p[v]; }
  const float inv = 1.f / s;
#pragma unroll
  for (int v = 0; v < 8; ++v) p[v] *= inv;
}

// Fragment layouts (bit-identical to round 2):
// Kf[bi][t][pq][kk][lane] : K[32pq+l%32][16kk+8*(l>>5)+i]   (A-op of St)
// Qf[bi][t][qq][kk][lane] : Q[32qq+l%32][16kk+8*(l>>5)+i]   (B-op of St)
// Vf[bi][t][pq][2kk2+hh][lane] : V[32pq+16kk2+8*(l>>5)+i][32hh+l%32] (B-op PV)
__global__ __launch_bounds__(256) void prep_kernel(
    const float* __restrict__ x, const float* __restrict__ WKw,
    const float* __restrict__ WQw, const float* __restrict__ WVw,
    const float* __restrict__ Wpred, short* __restrict__ Qf,
    short* __restrict__ Kf, short* __restrict__ Vf, float* __restrict__ V0f) {
  const int t = blockIdx.x, ih = blockIdx.y, b = blockIdx.z;
  const int bi = b * NH + ih;
  const int tid = threadIdx.x;

  // bf16 tiles, 128B rows, XOR-swizzled: byte = row*128 + (col2 ^ ((row&7)<<4))
  __shared__ alignas(16) char smem[5 * 8192];
  char* const Ksb = smem;              // K row-major [p][h]
  char* const Vtb = smem + 8192;       // V col-major [h][p]
  char* const Q0b = smem + 16384;      // Q0 row-major [q][e]
  char* const WpT = smem + 24576;      // Wp transposed [f][e]
  char* const Qsb = smem + 32768;      // Q row-major [q][f]

  // ---- Wp softmax -> WpT (transposed, bf16, swizzled) ----
  {
    const int e = tid >> 2, sg = tid & 3;
    const float* wr = Wpred + (size_t)(ih * 64 + e) * 64 + sg * 16;
    float e16[16];
    float mx = -1e30f;
#pragma unroll
    for (int j = 0; j < 16; ++j) { e16[j] = wr[j]; mx = fmaxf(mx, e16[j]); }
    mx = fmaxf(mx, __shfl_xor(mx, 1, 4));
    mx = fmaxf(mx, __shfl_xor(mx, 2, 4));
    float s = 0.f;
#pragma unroll
    for (int j = 0; j < 16; ++j) { e16[j] = __expf(e16[j] - mx); s += e16[j]; }
    s += __shfl_xor(s, 1, 4);
    s += __shfl_xor(s, 2, 4);
    const float inv = 1.f / s;
#pragma unroll
    for (int j = 0; j < 16; ++j) {
      const int f = sg * 16 + j;
      const unsigned pz = cvtpk(e16[j] * inv, e16[j] * inv);
      *(unsigned short*)&WpT[f * 128 + ((2 * e) ^ ((f & 7) << 4))] =
          (unsigned short)pz;
    }
  }

  float pk[8], pq8[8], pv[8];
  {
    float w[8];
#pragma unroll
    for (int v = 0; v < 8; ++v) w[v] = WKw[ih * 8 + v];
    softmax8(w, pk);
#pragma unroll
    for (int v = 0; v < 8; ++v) w[v] = WQw[ih * 8 + v];
    softmax8(w, pq8);
#pragma unroll
    for (int v = 0; v < 8; ++v) w[v] = WVw[ih * 8 + v];
    softmax8(w, pv);
  }

  // ---- Stage A: 4x4 register block of the mixes, float4 x loads ----
  const int rg = tid >> 4, eg = tid & 15;
  const int r0 = rg * 4, e0 = eg * 4;
  float ka[4][4], qa[4][4], va[4][4];
#pragma unroll
  for (int i2 = 0; i2 < 4; ++i2)
#pragma unroll
    for (int j = 0; j < 4; ++j) { ka[i2][j] = 0.f; qa[i2][j] = 0.f; va[i2][j] = 0.f; }

  const float* xb = x + ((size_t)(b * NCTX + t * 64 + r0)) * DIN + e0;
#pragma unroll
  for (int v = 0; v < 8; ++v) {
#pragma unroll
    for (int i2 = 0; i2 < 4; ++i2) {
      const float4 xv = *(const float4*)(xb + (size_t)i2 * DIN + v * 64);
      ka[i2][0] = fmaf(pk[v], xv.x, ka[i2][0]);
      ka[i2][1] = fmaf(pk[v], xv.y, ka[i2][1]);
      ka[i2][2] = fmaf(pk[v], xv.z, ka[i2][2]);
      ka[i2][3] = fmaf(pk[v], xv.w, ka[i2][3]);
      qa[i2][0] = fmaf(pq8[v], xv.x, qa[i2][0]);
      qa[i2][1] = fmaf(pq8[v], xv.y, qa[i2][1]);
      qa[i2][2] = fmaf(pq8[v], xv.z, qa[i2][2]);
      qa[i2][3] = fmaf(pq8[v], xv.w, qa[i2][3]);
      va[i2][0] = fmaf(pv[v], xv.x, va[i2][0]);
      va[i2][1] = fmaf(pv[v], xv.y, va[i2][1]);
      va[i2][2] = fmaf(pv[v], xv.z, va[i2][2]);
      va[i2][3] = fmaf(pv[v], xv.w, va[i2][3]);
    }
  }

  // V[0][*] in f32 for the attn correction term
  if (t == 0 && rg == 0) {
    *(float4*)(V0f + bi * 64 + e0) =
        make_float4(va[0][0], va[0][1], va[0][2], va[0][3]);
  }

  // bf16 LDS writes (K, Q0 row-major; V col-major)
#pragma unroll
  for (int i2 = 0; i2 < 4; ++i2) {
    const int r = r0 + i2;
    const int boff = (2 * e0) ^ ((r & 7) << 4);
    *(uint2*)&Ksb[r * 128 + boff] =
        make_uint2(cvtpk(ka[i2][0], ka[i2][1]), cvtpk(ka[i2][2], ka[i2][3]));
    *(uint2*)&Q0b[r * 128 + boff] =
        make_uint2(cvtpk(qa[i2][0], qa[i2][1]), cvtpk(qa[i2][2], qa[i2][3]));
  }
#pragma unroll
  for (int j = 0; j < 4; ++j) {
    const int rr = e0 + j;
    *(uint2*)&Vtb[rr * 128 + ((2 * r0) ^ ((rr & 7) << 4))] =
        make_uint2(cvtpk(va[0][j], va[1][j]), cvtpk(va[2][j], va[3][j]));
  }
  __syncthreads();

  const int wv = tid >> 6;
  const int l = tid & 63;
  const int lm = l & 31;
  const int hi = l >> 5;

  // ---- K/V fragment emission (overlaps with MFMA below) ----
  const size_t fbase = (size_t)bi * 8192 + (size_t)t * 512;
#pragma unroll
  for (int c = 0; c < 2; ++c) {
    const int idx = c * 256 + tid;
    const int pq = idx >> 8, j = (idx >> 6) & 3, ll = idx & 63;
    const int krow = 32 * pq + (ll & 31);
    const i32x4 kfr = *(const i32x4*)
        &Ksb[krow * 128 + ((32 * j + 16 * (ll >> 5)) ^ ((krow & 7) << 4))];
    ((i32x4*)Kf)[fbase + idx] = kfr;
    const int vrow = 32 * (j & 1) + (ll & 31);
    const i32x4 vfr = *(const i32x4*)
        &Vtb[vrow * 128 +
             ((64 * pq + 32 * (j >> 1) + 16 * (ll >> 5)) ^ ((vrow & 7) << 4))];
    ((i32x4*)Vf)[fbase + idx] = vfr;
  }

  // ---- Q = Q0 @ Wp via MFMA (wave quadrant qq x ff) ----
  {
    const int qq = wv & 1, ff = wv >> 1;
    f32x16 dreg;
#pragma unroll
    for (int r = 0; r < 16; ++r) dreg[r] = 0.f;
    const int arow = 32 * qq + lm;
    const int brow = 32 * ff + lm;
#pragma unroll
    for (int kk = 0; kk < 4; ++kk) {
      const i32x4 af = *(const i32x4*)
          &Q0b[arow * 128 + ((32 * kk + 16 * hi) ^ ((arow & 7) << 4))];
      const i32x4 bfr = *(const i32x4*)
          &WpT[brow * 128 + ((32 * kk + 16 * hi) ^ ((brow & 7) << 4))];
      dreg = __builtin_amdgcn_mfma_f32_32x32x16_bf16(asbf(af), asbf(bfr),
                                                     dreg, 0, 0, 0);
    }
#pragma unroll
    for (int r = 0; r < 16; ++r) {
      const int q = 32 * qq + (r & 3) + 8 * (r >> 2) + 4 * hi;
      const int f = 32 * ff + lm;
      const unsigned pz = cvtpk(dreg[r], dreg[r]);
      *(unsigned short*)&Qsb[q * 128 + ((2 * f) ^ ((q & 7) << 4))] =
          (unsigned short)pz;
    }
  }
  __syncthreads();

  // ---- Q fragment emission ----
#pragma unroll
  for (int c = 0; c < 2; ++c) {
    const int idx = c * 256 + tid;
    const int qq2 = idx >> 8, kk = (idx >> 6) & 3, ll = idx & 63;
    const int row = 32 * qq2 + (ll & 31);
    const i32x4 qfr = *(const i32x4*)
        &Qsb[row * 128 + ((32 * kk + 16 * (ll >> 5)) ^ ((row & 7) << 4))];
    ((i32x4*)Qf)[fbase + idx] = qfr;
  }
}

// Kernel 2: MFMA attention. One block per (bi, qt), 4 waves: pq=wv&1, qq=wv>>1.
__global__ __launch_bounds__(256) void attn_kernel(
    const short* __restrict__ Qf, const short* __restrict__ Kf,
    const short* __restrict__ Vf, const float* __restrict__ V0f,
    float* __restrict__ out) {
  const int bx = blockIdx.x;
  const int a = bx >> 5;
  const int bi = bx & 31;
  const int qt = (a < 8) ? (15 - a) : (a - 8);  // heavy-first, pair-sum 15
  const int b = bi >> 3, ih = bi & 7;
  const int tid = threadIdx.x;
  const int wv = tid >> 6;
  const int l = tid & 63;
  const int hi = l >> 5;
  const int lm = l & 31;
  const int pq = wv & 1;
  const int qq = wv >> 1;

  __shared__ float num_l[2][32][64];
  __shared__ float rdn[2][2][32];
  __shared__ float rsw[2][2][32];
  __shared__ float rp0[2][32];
  __shared__ float rdw[2][32];
  __shared__ float rinv[2][32];

  const i32x4* Qp = (const i32x4*)Qf + (size_t)bi * 8192 + (size_t)qt * 512 +
                    qq * 256;
  const i32x4* Kp = (const i32x4*)Kf + (size_t)bi * 8192 + pq * 256;
  const i32x4* Vp = (const i32x4*)Vf + (size_t)bi * 8192 + pq * 256;

  bf16x8 qfr[4];
#pragma unroll
  for (int kk = 0; kk < 4; ++kk) qfr[kk] = asbf(Qp[kk * 64 + l]);

  const float v0a = V0f[bi * 64 + lm];
  const float v0b = V0f[bi * 64 + 32 + lm];

  f32x16 num0, num1;
#pragma unroll
  for (int r = 0; r < 16; ++r) { num0[r] = 0.f; num1[r] = 0.f; }
  float den = 0.f, srw = 0.f, pre0 = 0.f;
  const int qg = qt * 64 + 32 * qq + lm;
  const float BC = 0.125f / 1023.0f;

  i32x4 kA[4], vA[4], kB[4], vB[4];

#define LOADKV(PT, S)                                                   \
  do {                                                                  \
    const size_t o_ = (size_t)(PT) * 512;                               \
    _Pragma("unroll") for (int kk = 0; kk < 4; ++kk)                    \
        k##S[kk] = Kp[o_ + kk * 64 + l];                                \
    _Pragma("unroll") for (int j = 0; j < 4; ++j)                       \
        v##S[j] = Vp[o_ + j * 64 + l];                                  \
  } while (0)

#define STEP(PT, S)                                                          \
  do {                                                                       \
    f32x16 st;                                                               \
    _Pragma("unroll") for (int r = 0; r < 16; ++r) st[r] = 0.f;              \
    __builtin_amdgcn_s_setprio(1);                                           \
    _Pragma("unroll") for (int kk = 0; kk < 4; ++kk) st =                    \
        __builtin_amdgcn_mfma_f32_32x32x16_bf16(asbf(k##S[kk]), qfr[kk], st, \
                                                0, 0, 0);                    \
    __builtin_amdgcn_s_setprio(0);                                           \
    const int pb_ = (PT) * 64 + 32 * pq + 4 * hi;                            \
    float w_[16];                                                            \
    _Pragma("unroll") for (int r = 0; r < 16; ++r) {                         \
      const int pg = pb_ + ((r & 3) + 8 * (r >> 2));                         \
      const int d = qg - pg;                                                 \
      const float pre = st[r];                                               \
      const float b8 = (d == 0) ? -0.25f : fmaf((float)d, -BC, BC);          \
      const bool ok = d >= 0;                                                \
      const float ww =                                                       \
          ok ? __expf(fmaf(0.125f, __logf(pre + 1e-20f), b8)) : 0.f;         \
      den += ww;                                                             \
      srw += ok ? pre : 0.f;                                                 \
      w_[r] = ww;                                                            \
    }                                                                        \
    if ((PT) == 0 && pq == 0 && hi == 0) pre0 = st[0];                       \
    _Pragma("unroll") for (int c = 0; c < 2; ++c) {                          \
      const unsigned P01 = cvtpk(w_[8 * c + 0], w_[8 * c + 1]);              \
      const unsigned P23 = cvtpk(w_[8 * c + 2], w_[8 * c + 3]);              \
      const unsigned P45 = cvtpk(w_[8 * c + 4], w_[8 * c + 5]);              \
      const unsigned P67 = cvtpk(w_[8 * c + 6], w_[8 * c + 7]);              \
      const unsigned X01 = (unsigned)__shfl_xor((int)P01, 32, 64);           \
      const unsigned X23 = (unsigned)__shfl_xor((int)P23, 32, 64);           \
      const unsigned X45 = (unsigned)__shfl_xor((int)P45, 32, 64);           \
      const unsigned X67 = (unsigned)__shfl_xor((int)P67, 32, 64);           \
      const bool h1 = hi != 0;                                               \
      const bf16x8 wf = mk8(h1 ? X45 : P01, h1 ? X67 : P23, h1 ? P45 : X01,  \
                            h1 ? P67 : X23);                                 \
      __builtin_amdgcn_s_setprio(1);                                         \
      num0 = __builtin_amdgcn_mfma_f32_32x32x16_bf16(wf, asbf(v##S[2 * c]),  \
                                                     num0, 0, 0, 0);         \
      num1 = __builtin_amdgcn_mfma_f32_32x32x16_bf16(                        \
          wf, asbf(v##S[2 * c + 1]), num1, 0, 0, 0);                         \
      __builtin_amdgcn_s_setprio(0);                                         \
    }                                                                        \
  } while (0)

  LOADKV(0, A);
  for (int pt = 0; pt <= qt; pt += 2) {
    if (pt + 1 <= qt) LOADKV(pt + 1, B);
    STEP(pt, A);
    if (pt + 1 > qt) break;
    if (pt + 2 <= qt) LOADKV(pt + 2, A);
    STEP(pt + 1, B);
  }

  // cross-wave (pq) reduction
  const float dsum = den + __shfl_xor(den, 32, 64);
  const float ssum = srw + __shfl_xor(srw, 32, 64);
  if (hi == 0) {
    rdn[qq][pq][lm] = dsum;
    rsw[qq][pq][lm] = ssum;
    if (pq == 0) rp0[qq][lm] = pre0;
  }
  if (pq == 1) {
#pragma unroll
    for (int r = 0; r < 16; ++r) {
      const int row = (r & 3) + 8 * (r >> 2) + 4 * hi;
      num_l[qq][row][lm] = num0[r];
      num_l[qq][row][32 + lm] = num1[r];
    }
  }
  __syncthreads();
  if (pq == 1 && hi == 0) {
    const int q = lm;
    const float dtot = rdn[qq][0][q] + rdn[qq][1][q];
    const float stot = rsw[qq][0][q] + rsw[qq][1][q];
    const float p0v = rp0[qq][q];
    const float ms = stot / (stot + 1e-10f);
    const float add = fmaxf(1.f - ms, 0.f);
    const int qgq = qt * 64 + qq * 32 + q;
    const float b8 =
        (qgq == 0) ? -0.25f : (1.0f - (float)qgq) * (0.125f / 1023.0f);
    const float w0n = __expf(fmaf(0.125f, __logf(p0v + add + 1e-20f), b8));
    const float w0o = __expf(fmaf(0.125f, __logf(p0v + 1e-20f), b8));
    const float dwv = w0n - w0o;
    rdw[qq][q] = dwv;
    rinv[qq][q] = 1.f / (dtot + dwv);
  }
  __syncthreads();
  if (pq == 0) {
#pragma unroll
    for (int r = 0; r < 16; ++r) {
      const int row = (r & 3) + 8 * (r >> 2) + 4 * hi;
      const int qgq = qt * 64 + qq * 32 + row;
      const float dwv = rdw[qq][row];
      const float iv = rinv[qq][row];
      const float o0 = (num0[r] + num_l[qq][row][lm] + dwv * v0a) * iv;
      const float o1 = (num1[r] + num_l[qq][row][32 + lm] + dwv * v0b) * iv;
      float* op = out + ((size_t)b * NCTX + qgq) * DIN + ih * DH;
      op[lm] = o0;
      op[32 + lm] = o1;
    }
  }
#undef LOADKV
#undef STEP
}

extern "C" void kernel_launch(void* const* d_in, const int* in_sizes, int n_in,
                              void* d_out, int out_size, void* d_ws,
                              size_t ws_size, hipStream_t stream) {
  const float* x = (const float*)d_in[0];
  const float* WKw = (const float*)d_in[2];
  const float* WQw = (const float*)d_in[3];
  const float* WVw = (const float*)d_in[4];
  const float* Wpred = (const float*)d_in[5];
  float* out = (float*)d_out;

  short* Qf = (short*)((char*)d_ws + QF_OFF);
  short* Kf = (short*)((char*)d_ws + KF_OFF);
  short* Vf = (short*)((char*)d_ws + VF_OFF);
  float* V0f = (float*)((char*)d_ws + V0_OFF);

  dim3 block(256);
  dim3 grid1(16, NH, 4);
  hipLaunchKernelGGL(prep_kernel, grid1, block, 0, stream, x, WKw, WQw, WVw,
                     Wpred, Qf, Kf, Vf, V0f);
  dim3 grid2(512);
  hipLaunchKernelGGL(attn_kernel, grid2, block, 0, stream, Qf, Kf, Vf, V0f,
                     out);
}

// Round 4
// 31.778 us; speedup vs baseline: 6.5760x; 1.2719x over previous
//
#include <hip/hip_runtime.h>
#include <math.h>

#define NCTX 1024
#define DIN 512
#define NH 8
#define DH 64

typedef float f32x16 __attribute__((ext_vector_type(16)));
typedef short bf16x8 __attribute__((ext_vector_type(8)));
typedef int i32x4 __attribute__((ext_vector_type(4)));

// ws byte offsets: Qf 4MB | Kf 4MB | Vf 4MB | V0f 8KB
#define QF_OFF 0
#define KF_OFF (4u * 1024u * 1024u)
#define VF_OFF (8u * 1024u * 1024u)
#define V0_OFF (12u * 1024u * 1024u)

__device__ __forceinline__ bf16x8 asbf(i32x4 v) {
  union { i32x4 i; bf16x8 h; } u;
  u.i = v;
  return u.h;
}

__device__ __forceinline__ bf16x8 mk8(unsigned a, unsigned b, unsigned c,
                                      unsigned d) {
  union { unsigned u[4]; bf16x8 h; } x;
  x.u[0] = a; x.u[1] = b; x.u[2] = c; x.u[3] = d;
  return x.h;
}

__device__ __forceinline__ unsigned cvtpk(float lo, float hi_) {
  unsigned r;
  asm("v_cvt_pk_bf16_f32 %0, %1, %2" : "=v"(r) : "v"(lo), "v"(hi_));
  return r;
}

__device__ __forceinline__ void softmax8(const float* __restrict__ w,
                                         float* __restrict__ p) {
  float mx = w[0];
#pragma unroll
  for (int v = 1; v < 8; ++v) mx = fmaxf(mx, w[v]);
  float s = 0.f;
#pragma unroll
  for (int v = 0; v < 8; ++v) { p[v] = expf(w[v] - mx); s += p[v]; }
  const float inv = 1.f / s;
#pragma unroll
  for (int v = 0; v < 8; ++v) p[v] *= inv;
}

// Fragment layouts:
// Kf[bi][t][pq][kk][lane] : K[32pq+l%32][16kk+8*(l>>5)+i]   (A-op of St)
// Qf[bi][t][qq][kk][lane] : Q[32qq+l%32][16kk+8*(l>>5)+i]   (B-op of St)
// Vf[bi][t][pq][2kk2+hh][lane] : V[32pq+16kk2+8*(l>>5)+i][32hh+l%32] (B-op PV)
__global__ __launch_bounds__(256) void prep_kernel(
    const float* __restrict__ x, const float* __restrict__ WKw,
    const float* __restrict__ WQw, const float* __restrict__ WVw,
    const float* __restrict__ Wpred, short* __restrict__ Qf,
    short* __restrict__ Kf, short* __restrict__ Vf, float* __restrict__ V0f) {
  const int t = blockIdx.x, ih = blockIdx.y, b = blockIdx.z;
  const int bi = b * NH + ih;
  const int tid = threadIdx.x;

  // bf16 tiles, 128B rows, XOR-swizzled: byte = row*128 + (col2 ^ ((row&7)<<4))
  __shared__ alignas(16) char smem[5 * 8192];
  char* const Ksb = smem;              // K row-major [p][h]
  char* const Vtb = smem + 8192;       // V col-major [h][p]
  char* const Q0b = smem + 16384;      // Q0 row-major [q][e]
  char* const WpT = smem + 24576;      // Wp transposed [f][e]
  char* const Qsb = smem + 32768;      // Q row-major [q][f]

  // ---- Wp softmax -> WpT (transposed, bf16, swizzled) ----
  {
    const int e = tid >> 2, sg = tid & 3;
    const float* wr = Wpred + (size_t)(ih * 64 + e) * 64 + sg * 16;
    float e16[16];
    float mx = -1e30f;
#pragma unroll
    for (int j = 0; j < 16; ++j) { e16[j] = wr[j]; mx = fmaxf(mx, e16[j]); }
    mx = fmaxf(mx, __shfl_xor(mx, 1, 4));
    mx = fmaxf(mx, __shfl_xor(mx, 2, 4));
    float s = 0.f;
#pragma unroll
    for (int j = 0; j < 16; ++j) { e16[j] = __expf(e16[j] - mx); s += e16[j]; }
    s += __shfl_xor(s, 1, 4);
    s += __shfl_xor(s, 2, 4);
    const float inv = 1.f / s;
#pragma unroll
    for (int j = 0; j < 16; ++j) {
      const int f = sg * 16 + j;
      const unsigned pz = cvtpk(e16[j] * inv, e16[j] * inv);
      *(unsigned short*)&WpT[f * 128 + ((2 * e) ^ ((f & 7) << 4))] =
          (unsigned short)pz;
    }
  }

  float pk[8], pq8[8], pv[8];
  {
    float w[8];
#pragma unroll
    for (int v = 0; v < 8; ++v) w[v] = WKw[ih * 8 + v];
    softmax8(w, pk);
#pragma unroll
    for (int v = 0; v < 8; ++v) w[v] = WQw[ih * 8 + v];
    softmax8(w, pq8);
#pragma unroll
    for (int v = 0; v < 8; ++v) w[v] = WVw[ih * 8 + v];
    softmax8(w, pv);
  }

  // ---- Stage A: 4x4 register block of the mixes, float4 x loads ----
  const int rg = tid >> 4, eg = tid & 15;
  const int r0 = rg * 4, e0 = eg * 4;
  float ka[4][4], qa[4][4], va[4][4];
#pragma unroll
  for (int i2 = 0; i2 < 4; ++i2)
#pragma unroll
    for (int j = 0; j < 4; ++j) { ka[i2][j] = 0.f; qa[i2][j] = 0.f; va[i2][j] = 0.f; }

  const float* xb = x + ((size_t)(b * NCTX + t * 64 + r0)) * DIN + e0;
#pragma unroll
  for (int v = 0; v < 8; ++v) {
#pragma unroll
    for (int i2 = 0; i2 < 4; ++i2) {
      const float4 xv = *(const float4*)(xb + (size_t)i2 * DIN + v * 64);
      ka[i2][0] = fmaf(pk[v], xv.x, ka[i2][0]);
      ka[i2][1] = fmaf(pk[v], xv.y, ka[i2][1]);
      ka[i2][2] = fmaf(pk[v], xv.z, ka[i2][2]);
      ka[i2][3] = fmaf(pk[v], xv.w, ka[i2][3]);
      qa[i2][0] = fmaf(pq8[v], xv.x, qa[i2][0]);
      qa[i2][1] = fmaf(pq8[v], xv.y, qa[i2][1]);
      qa[i2][2] = fmaf(pq8[v], xv.z, qa[i2][2]);
      qa[i2][3] = fmaf(pq8[v], xv.w, qa[i2][3]);
      va[i2][0] = fmaf(pv[v], xv.x, va[i2][0]);
      va[i2][1] = fmaf(pv[v], xv.y, va[i2][1]);
      va[i2][2] = fmaf(pv[v], xv.z, va[i2][2]);
      va[i2][3] = fmaf(pv[v], xv.w, va[i2][3]);
    }
  }

  // V[0][*] in f32 for the attn correction term
  if (t == 0 && rg == 0) {
    *(float4*)(V0f + bi * 64 + e0) =
        make_float4(va[0][0], va[0][1], va[0][2], va[0][3]);
  }

  // bf16 LDS writes (K, Q0 row-major; V col-major)
#pragma unroll
  for (int i2 = 0; i2 < 4; ++i2) {
    const int r = r0 + i2;
    const int boff = (2 * e0) ^ ((r & 7) << 4);
    *(uint2*)&Ksb[r * 128 + boff] =
        make_uint2(cvtpk(ka[i2][0], ka[i2][1]), cvtpk(ka[i2][2], ka[i2][3]));
    *(uint2*)&Q0b[r * 128 + boff] =
        make_uint2(cvtpk(qa[i2][0], qa[i2][1]), cvtpk(qa[i2][2], qa[i2][3]));
  }
#pragma unroll
  for (int j = 0; j < 4; ++j) {
    const int rr = e0 + j;
    *(uint2*)&Vtb[rr * 128 + ((2 * r0) ^ ((rr & 7) << 4))] =
        make_uint2(cvtpk(va[0][j], va[1][j]), cvtpk(va[2][j], va[3][j]));
  }
  __syncthreads();

  const int wv = tid >> 6;
  const int l = tid & 63;
  const int lm = l & 31;
  const int hi = l >> 5;

  // ---- K/V fragment emission ----
  const size_t fbase = (size_t)bi * 8192 + (size_t)t * 512;
#pragma unroll
  for (int c = 0; c < 2; ++c) {
    const int idx = c * 256 + tid;
    const int pq = idx >> 8, j = (idx >> 6) & 3, ll = idx & 63;
    const int krow = 32 * pq + (ll & 31);
    const i32x4 kfr = *(const i32x4*)
        &Ksb[krow * 128 + ((32 * j + 16 * (ll >> 5)) ^ ((krow & 7) << 4))];
    ((i32x4*)Kf)[fbase + idx] = kfr;
    const int vrow = 32 * (j & 1) + (ll & 31);
    const i32x4 vfr = *(const i32x4*)
        &Vtb[vrow * 128 +
             ((64 * pq + 32 * (j >> 1) + 16 * (ll >> 5)) ^ ((vrow & 7) << 4))];
    ((i32x4*)Vf)[fbase + idx] = vfr;
  }

  // ---- Q = Q0 @ Wp via MFMA (wave quadrant qq x ff) ----
  {
    const int qq = wv & 1, ff = wv >> 1;
    f32x16 dreg;
#pragma unroll
    for (int r = 0; r < 16; ++r) dreg[r] = 0.f;
    const int arow = 32 * qq + lm;
    const int brow = 32 * ff + lm;
#pragma unroll
    for (int kk = 0; kk < 4; ++kk) {
      const i32x4 af = *(const i32x4*)
          &Q0b[arow * 128 + ((32 * kk + 16 * hi) ^ ((arow & 7) << 4))];
      const i32x4 bfr = *(const i32x4*)
          &WpT[brow * 128 + ((32 * kk + 16 * hi) ^ ((brow & 7) << 4))];
      dreg = __builtin_amdgcn_mfma_f32_32x32x16_bf16(asbf(af), asbf(bfr),
                                                     dreg, 0, 0, 0);
    }
#pragma unroll
    for (int r = 0; r < 16; ++r) {
      const int q = 32 * qq + (r & 3) + 8 * (r >> 2) + 4 * hi;
      const int f = 32 * ff + lm;
      const unsigned pz = cvtpk(dreg[r], dreg[r]);
      *(unsigned short*)&Qsb[q * 128 + ((2 * f) ^ ((q & 7) << 4))] =
          (unsigned short)pz;
    }
  }
  __syncthreads();

  // ---- Q fragment emission ----
#pragma unroll
  for (int c = 0; c < 2; ++c) {
    const int idx = c * 256 + tid;
    const int qq2 = idx >> 8, kk = (idx >> 6) & 3, ll = idx & 63;
    const int row = 32 * qq2 + (ll & 31);
    const i32x4 qfr = *(const i32x4*)
        &Qsb[row * 128 + ((32 * kk + 16 * (ll >> 5)) ^ ((row & 7) << 4))];
    ((i32x4*)Qf)[fbase + idx] = qfr;
  }
}

// Transform constants: log2 domain if the raw builtins exist, else natural.
#if __has_builtin(__builtin_amdgcn_exp2f) && __has_builtin(__builtin_amdgcn_logf)
#define T_LOG(x) __builtin_amdgcn_logf(x)
#define T_EXP(x) __builtin_amdgcn_exp2f(x)
#define T_L 1.7628215e-4f   /* 0.125/(1023*ln2) */
#define T_DIAG (-0.36067376f) /* -0.25*log2(e) */
#else
#define T_LOG(x) __logf(x)
#define T_EXP(x) __expf(x)
#define T_L 1.2219941e-4f   /* 0.125/1023 */
#define T_DIAG (-0.25f)
#endif

// Kernel 2: MFMA attention, software-pipelined across p-steps.
__global__ __launch_bounds__(256, 2) void attn_kernel(
    const short* __restrict__ Qf, const short* __restrict__ Kf,
    const short* __restrict__ Vf, const float* __restrict__ V0f,
    float* __restrict__ out) {
  const int bx = blockIdx.x;
  const int a = bx >> 5;
  const int bi = bx & 31;
  const int qt = (a < 8) ? (15 - a) : (a - 8);  // heavy-first, pair-sum 15
  const int b = bi >> 3, ih = bi & 7;
  const int tid = threadIdx.x;
  const int wv = tid >> 6;
  const int l = tid & 63;
  const int hi = l >> 5;
  const int lm = l & 31;
  const int pq = wv & 1;
  const int qq = wv >> 1;

  __shared__ float num_l[2][32][64];
  __shared__ float rdn[2][2][32];
  __shared__ float rsw[2][2][32];
  __shared__ float rp0[2][32];
  __shared__ float rdw[2][32];
  __shared__ float rinv[2][32];

  const i32x4* Qp = (const i32x4*)Qf + (size_t)bi * 8192 + (size_t)qt * 512 +
                    qq * 256;
  const i32x4* Kp = (const i32x4*)Kf + (size_t)bi * 8192 + pq * 256;
  const i32x4* Vp = (const i32x4*)Vf + (size_t)bi * 8192 + pq * 256;

  bf16x8 qfr[4];
#pragma unroll
  for (int kk = 0; kk < 4; ++kk) qfr[kk] = asbf(Qp[kk * 64 + l]);

  const float v0a = V0f[bi * 64 + lm];
  const float v0b = V0f[bi * 64 + 32 + lm];

  f32x16 num0, num1, stA, stB;
#pragma unroll
  for (int r = 0; r < 16; ++r) { num0[r] = 0.f; num1[r] = 0.f; }
  float den = 0.f, srw = 0.f, pre0 = 0.f;
  const int qg = qt * 64 + 32 * qq + lm;
  const int qpb = qg - 32 * pq - 4 * hi;  // D0 = qpb - 64*PT

  i32x4 kA[4], vA[4], kB[4], vB[4];

#define LOADKV(PT, S)                                                   \
  do {                                                                  \
    const size_t o_ = (size_t)(PT) * 512;                               \
    _Pragma("unroll") for (int kk = 0; kk < 4; ++kk)                    \
        k##S[kk] = Kp[o_ + kk * 64 + l];                                \
    _Pragma("unroll") for (int j = 0; j < 4; ++j)                       \
        v##S[j] = Vp[o_ + j * 64 + l];                                  \
  } while (0)

#define QKSTEP(S)                                                            \
  do {                                                                       \
    _Pragma("unroll") for (int r = 0; r < 16; ++r) st##S[r] = 0.f;           \
    __builtin_amdgcn_s_setprio(1);                                           \
    _Pragma("unroll") for (int kk = 0; kk < 4; ++kk) st##S =                 \
        __builtin_amdgcn_mfma_f32_32x32x16_bf16(asbf(k##S[kk]), qfr[kk],     \
                                                st##S, 0, 0, 0);             \
    __builtin_amdgcn_s_setprio(0);                                           \
  } while (0)

// Process step PT from CUR buffers; issue QK for PT+1 (NXT) mid-phase;
// prefetch PT+2 into CUR at the end.
#define PHASE(PT, CUR, NXT)                                                  \
  do {                                                                       \
    const int D0 = qpb - 64 * (PT);                                          \
    const float B0 = (1.0f - (float)D0) * T_L;                               \
    float w_[16];                                                            \
    _Pragma("unroll") for (int r = 0; r < 16; ++r) {                         \
      const int ro = (r & 3) + 8 * (r >> 2);                                 \
      const float pre = st##CUR[r];                                          \
      float b2 = B0 + (float)ro * T_L;                                       \
      b2 = (D0 == ro) ? T_DIAG : b2;                                         \
      b2 = (D0 < ro) ? -1e38f : b2;                                          \
      w_[r] = T_EXP(fmaf(0.125f, T_LOG(pre + 1e-20f), b2));                  \
      den += w_[r];                                                          \
      srw += (D0 >= ro) ? pre : 0.f;                                         \
    }                                                                        \
    if ((PT) == 0 && pq == 0 && hi == 0) pre0 = st##CUR[0];                  \
    if ((PT) + 1 <= qt) QKSTEP(NXT);                                         \
    const unsigned P0 = cvtpk(w_[0], w_[1]), P1 = cvtpk(w_[2], w_[3]);       \
    const unsigned P2 = cvtpk(w_[4], w_[5]), P3 = cvtpk(w_[6], w_[7]);       \
    const unsigned P4 = cvtpk(w_[8], w_[9]), P5 = cvtpk(w_[10], w_[11]);     \
    const unsigned P6 = cvtpk(w_[12], w_[13]), P7 = cvtpk(w_[14], w_[15]);   \
    const unsigned X0 = (unsigned)__shfl_xor((int)P0, 32, 64);               \
    const unsigned X1 = (unsigned)__shfl_xor((int)P1, 32, 64);               \
    const unsigned X2 = (unsigned)__shfl_xor((int)P2, 32, 64);               \
    const unsigned X3 = (unsigned)__shfl_xor((int)P3, 32, 64);               \
    const unsigned X4 = (unsigned)__shfl_xor((int)P4, 32, 64);               \
    const unsigned X5 = (unsigned)__shfl_xor((int)P5, 32, 64);               \
    const unsigned X6 = (unsigned)__shfl_xor((int)P6, 32, 64);               \
    const unsigned X7 = (unsigned)__shfl_xor((int)P7, 32, 64);               \
    const bool h1 = hi != 0;                                                 \
    const bf16x8 wf0 = mk8(h1 ? X2 : P0, h1 ? X3 : P1, h1 ? P2 : X0,         \
                           h1 ? P3 : X1);                                    \
    const bf16x8 wf1 = mk8(h1 ? X6 : P4, h1 ? X7 : P5, h1 ? P6 : X4,         \
                           h1 ? P7 : X5);                                    \
    __builtin_amdgcn_s_setprio(1);                                           \
    num0 = __builtin_amdgcn_mfma_f32_32x32x16_bf16(wf0, asbf(v##CUR[0]),     \
                                                   num0, 0, 0, 0);           \
    num1 = __builtin_amdgcn_mfma_f32_32x32x16_bf16(wf0, asbf(v##CUR[1]),     \
                                                   num1, 0, 0, 0);           \
    num0 = __builtin_amdgcn_mfma_f32_32x32x16_bf16(wf1, asbf(v##CUR[2]),     \
                                                   num0, 0, 0, 0);           \
    num1 = __builtin_amdgcn_mfma_f32_32x32x16_bf16(wf1, asbf(v##CUR[3]),     \
                                                   num1, 0, 0, 0);           \
    __builtin_amdgcn_s_setprio(0);                                           \
    if ((PT) + 2 <= qt) LOADKV((PT) + 2, CUR);                               \
  } while (0)

  LOADKV(0, A);
  QKSTEP(A);
  if (qt >= 1) LOADKV(1, B);
  for (int pt = 0; pt <= qt; pt += 2) {
    PHASE(pt, A, B);
    if (pt + 1 > qt) break;
    PHASE(pt + 1, B, A);
  }

  // cross-wave (pq) reduction
  const float dsum = den + __shfl_xor(den, 32, 64);
  const float ssum = srw + __shfl_xor(srw, 32, 64);
  if (hi == 0) {
    rdn[qq][pq][lm] = dsum;
    rsw[qq][pq][lm] = ssum;
    if (pq == 0) rp0[qq][lm] = pre0;
  }
  if (pq == 1) {
#pragma unroll
    for (int r = 0; r < 16; ++r) {
      const int row = (r & 3) + 8 * (r >> 2) + 4 * hi;
      num_l[qq][row][lm] = num0[r];
      num_l[qq][row][32 + lm] = num1[r];
    }
  }
  __syncthreads();
  if (pq == 1 && hi == 0) {
    const int q = lm;
    const float dtot = rdn[qq][0][q] + rdn[qq][1][q];
    const float stot = rsw[qq][0][q] + rsw[qq][1][q];
    const float p0v = rp0[qq][q];
    const float ms = stot / (stot + 1e-10f);
    const float add = fmaxf(1.f - ms, 0.f);
    const int qgq = qt * 64 + qq * 32 + q;
    const float b8 =
        (qgq == 0) ? -0.25f : (1.0f - (float)qgq) * (0.125f / 1023.0f);
    const float w0n = __expf(fmaf(0.125f, __logf(p0v + add + 1e-20f), b8));
    const float w0o = __expf(fmaf(0.125f, __logf(p0v + 1e-20f), b8));
    const float dwv = w0n - w0o;
    rdw[qq][q] = dwv;
    rinv[qq][q] = 1.f / (dtot + dwv);
  }
  __syncthreads();
  if (pq == 0) {
#pragma unroll
    for (int r = 0; r < 16; ++r) {
      const int row = (r & 3) + 8 * (r >> 2) + 4 * hi;
      const int qgq = qt * 64 + qq * 32 + row;
      const float dwv = rdw[qq][row];
      const float iv = rinv[qq][row];
      const float o0 = (num0[r] + num_l[qq][row][lm] + dwv * v0a) * iv;
      const float o1 = (num1[r] + num_l[qq][row][32 + lm] + dwv * v0b) * iv;
      float* op = out + ((size_t)b * NCTX + qgq) * DIN + ih * DH;
      op[lm] = o0;
      op[32 + lm] = o1;
    }
  }
#undef LOADKV
#undef QKSTEP
#undef PHASE
}

extern "C" void kernel_launch(void* const* d_in, const int* in_sizes, int n_in,
                              void* d_out, int out_size, void* d_ws,
                              size_t ws_size, hipStream_t stream) {
  const float* x = (const float*)d_in[0];
  const float* WKw = (const float*)d_in[2];
  const float* WQw = (const float*)d_in[3];
  const float* WVw = (const float*)d_in[4];
  const float* Wpred = (const float*)d_in[5];
  float* out = (float*)d_out;

  short* Qf = (short*)((char*)d_ws + QF_OFF);
  short* Kf = (short*)((char*)d_ws + KF_OFF);
  short* Vf = (short*)((char*)d_ws + VF_OFF);
  float* V0f = (float*)((char*)d_ws + V0_OFF);

  dim3 block(256);
  dim3 grid1(16, NH, 4);
  hipLaunchKernelGGL(prep_kernel, grid1, block, 0, stream, x, WKw, WQw, WVw,
                     Wpred, Qf, Kf, Vf, V0f);
  dim3 grid2(512);
  hipLaunchKernelGGL(attn_kernel, grid2, block, 0, stream, Qf, Kf, Vf, V0f,
                     out);
}